// Round 2
// baseline (857.968 us; speedup 1.0000x reference)
//
#include <hip/hip_runtime.h>
#include <hip/hip_bf16.h>

#define NNODES 65536
#define NEDGES 262144
#define BATCH  64
#define HDIM   256

// ---------------------------------------------------------------------------
// K1: per-node u[n] = Wf[0:H] . x[n],  v[n] = Wf[H:2H] . x[n]
//     one wave per node, float4 per lane (64*16B = 1KB coalesced row read)
// ---------------------------------------------------------------------------
__global__ __launch_bounds__(256) void k_uv(
    const float* __restrict__ hidden, const int* __restrict__ node_idx,
    const float* __restrict__ Wf, float* __restrict__ u, float* __restrict__ v) {
  int gw   = (blockIdx.x * 256 + threadIdx.x) >> 6;   // global wave = node
  int lane = threadIdx.x & 63;
  if (gw >= NNODES) return;
  const float4* xr = (const float4*)(hidden + (size_t)node_idx[gw] * HDIM);
  float4 xv = xr[lane];
  float4 wa = ((const float4*)Wf)[lane];
  float4 wb = ((const float4*)Wf)[64 + lane];
  float su = xv.x*wa.x + xv.y*wa.y + xv.z*wa.z + xv.w*wa.w;
  float sv = xv.x*wb.x + xv.y*wb.y + xv.z*wb.z + xv.w*wb.w;
  #pragma unroll
  for (int off = 32; off > 0; off >>= 1) {
    su += __shfl_down(su, off);
    sv += __shfl_down(sv, off);
  }
  if (lane == 0) { u[gw] = su; v[gw] = sv; }
}

// ---------------------------------------------------------------------------
// K2: per-edge filter weight w_e = sigmoid(u[row]+v[col]+bf); deg[col] += w_e
// ---------------------------------------------------------------------------
__global__ __launch_bounds__(256) void k_edge_w(
    const int* __restrict__ ei, const float* __restrict__ u,
    const float* __restrict__ v, const float* __restrict__ bf,
    float* __restrict__ wbuf, float* __restrict__ deg) {
  int e = blockIdx.x * 256 + threadIdx.x;
  if (e >= NEDGES) return;
  int r = ei[e], c = ei[NEDGES + e];
  float t = u[r] + v[c] + bf[0];
  float w = 1.0f / (1.0f + __expf(-t));
  wbuf[e] = w;
  unsafeAtomicAdd(&deg[c], w);            // native global_atomic_add_f32
}

// ---------------------------------------------------------------------------
// K3: dis[n] = rsqrt(deg[n]+1) (self-loop weight 1); counts histogram
// ---------------------------------------------------------------------------
__global__ __launch_bounds__(256) void k_dis(
    const int* __restrict__ node_batch, const float* __restrict__ deg,
    float* __restrict__ dis, int* __restrict__ cnt) {
  int n = blockIdx.x * 256 + threadIdx.x;
  if (n >= NNODES) return;
  dis[n] = rsqrtf(deg[n] + 1.0f);
  atomicAdd(&cnt[node_batch[n]], 1);
}

// ---------------------------------------------------------------------------
// K4: agg[b][j] += coeff * x[node][j] over all edges (+ self loops).
//     One wave per work item; [B][H] fp32 accumulator privatized in LDS
//     (64KB). lane handles j = lane, lane+64, lane+128, lane+192 so each
//     ds_add_f32 hits banks lane%32 -> 2-way aliasing (free, m136).
//     Work items: [0,E) edges, [E,E+N) self loops.
// ---------------------------------------------------------------------------
__global__ __launch_bounds__(1024) void k_agg(
    const float* __restrict__ hidden, const int* __restrict__ node_idx,
    const int* __restrict__ ei, const int* __restrict__ node_batch,
    const float* __restrict__ wbuf, const float* __restrict__ dis,
    float* __restrict__ agg) {
  __shared__ float acc[BATCH * HDIM];       // 64 KB
  int tid = threadIdx.x;
  for (int i = tid; i < BATCH * HDIM; i += 1024) acc[i] = 0.0f;
  __syncthreads();
  int lane = tid & 63;
  int wid  = tid >> 6;                      // 0..15
  int gw   = blockIdx.x * 16 + wid;
  const int NW    = gridDim.x * 16;
  const int TOTAL = NEDGES + NNODES;
  for (int item = gw; item < TOTAL; item += NW) {
    float coeff; int b, node;
    if (item < NEDGES) {                    // wave-uniform branch
      int r = ei[item], c = ei[NEDGES + item];
      coeff = dis[r] * wbuf[item] * dis[c];
      b     = node_batch[c];
      node  = r;
    } else {
      int n = item - NEDGES;
      float dn = dis[n];
      coeff = dn * dn;                      // 1/deg
      b     = node_batch[n];
      node  = n;
    }
    const float* src = hidden + (size_t)node_idx[node] * HDIM;
    float* dst = acc + b * HDIM;
    unsafeAtomicAdd(&dst[lane],       coeff * src[lane]);
    unsafeAtomicAdd(&dst[lane + 64],  coeff * src[lane + 64]);
    unsafeAtomicAdd(&dst[lane + 128], coeff * src[lane + 128]);
    unsafeAtomicAdd(&dst[lane + 192], coeff * src[lane + 192]);
  }
  __syncthreads();
  for (int i = tid; i < BATCH * HDIM; i += 1024)
    unsafeAtomicAdd(&agg[i], acc[i]);
}

// ---------------------------------------------------------------------------
// K5: one block per batch b.
//     pooled[k] = (Wc[k,:] . agg[b,:]) / cnt[b] + bc[k]
//     out[b][h] = tanh(Wd[h,:] . pooled + bd[h])
// ---------------------------------------------------------------------------
__global__ __launch_bounds__(256) void k_final(
    const float* __restrict__ agg, const int* __restrict__ cnt,
    const float* __restrict__ Wc, const float* __restrict__ bc,
    const float* __restrict__ Wd, const float* __restrict__ bd,
    float* __restrict__ out) {
  __shared__ float s_in[HDIM];
  __shared__ float s_mid[HDIM];
  int b = blockIdx.x, tid = threadIdx.x;
  s_in[tid] = agg[b * HDIM + tid];
  __syncthreads();
  int lane = tid & 63, wid = tid >> 6;
  float inv = 1.0f / fmaxf((float)cnt[b], 1.0f);
  for (int kk = 0; kk < 64; ++kk) {
    int k = wid * 64 + kk;
    float4 wv = ((const float4*)(Wc + (size_t)k * HDIM))[lane];
    float4 av = ((const float4*)s_in)[lane];
    float p = wv.x*av.x + wv.y*av.y + wv.z*av.z + wv.w*av.w;
    #pragma unroll
    for (int off = 32; off > 0; off >>= 1) p += __shfl_down(p, off);
    if (lane == 0) s_mid[k] = p * inv + bc[k];
  }
  __syncthreads();
  for (int kk = 0; kk < 64; ++kk) {
    int k = wid * 64 + kk;
    float4 wv = ((const float4*)(Wd + (size_t)k * HDIM))[lane];
    float4 av = ((const float4*)s_mid)[lane];
    float p = wv.x*av.x + wv.y*av.y + wv.z*av.z + wv.w*av.w;
    #pragma unroll
    for (int off = 32; off > 0; off >>= 1) p += __shfl_down(p, off);
    if (lane == 0) out[b * HDIM + k] = tanhf(p + bd[k]);
  }
}

// ---------------------------------------------------------------------------
extern "C" void kernel_launch(void* const* d_in, const int* in_sizes, int n_in,
                              void* d_out, int out_size, void* d_ws, size_t ws_size,
                              hipStream_t stream) {
  const float* hidden     = (const float*)d_in[0];
  const int*   node_idx   = (const int*)  d_in[1];
  const int*   ei         = (const int*)  d_in[2];
  const int*   node_batch = (const int*)  d_in[3];
  const float* Wf         = (const float*)d_in[4];
  const float* bf         = (const float*)d_in[5];
  const float* Wc         = (const float*)d_in[6];
  const float* bc         = (const float*)d_in[7];
  const float* Wd         = (const float*)d_in[8];
  const float* bd         = (const float*)d_in[9];
  float* out = (float*)d_out;

  // workspace layout (floats); accumulators (agg, deg, cnt) zeroed every call
  float* ws   = (float*)d_ws;
  float* agg  = ws;                     // 16384
  float* deg  = agg + BATCH * HDIM;     // 65536
  int*   cnt  = (int*)(deg + NNODES);   // 64
  float* u    = (float*)(cnt + 64);     // 65536
  float* v    = u + NNODES;             // 65536
  float* dis  = v + NNODES;             // 65536
  float* wbuf = dis + NNODES;           // 262144

  (void)hipMemsetAsync(agg, 0, (BATCH * HDIM + NNODES + 64) * sizeof(float), stream);

  k_uv    <<<NNODES / 4,   256,  0, stream>>>(hidden, node_idx, Wf, u, v);
  k_edge_w<<<NEDGES / 256, 256,  0, stream>>>(ei, u, v, bf, wbuf, deg);
  k_dis   <<<NNODES / 256, 256,  0, stream>>>(node_batch, deg, dis, cnt);
  k_agg   <<<512,          1024, 0, stream>>>(hidden, node_idx, ei, node_batch, wbuf, dis, agg);
  k_final <<<BATCH,        256,  0, stream>>>(agg, cnt, Wc, bc, Wd, bd, out);
}

// Round 3
// 594.322 us; speedup vs baseline: 1.4436x; 1.4436x over previous
//
#include <hip/hip_runtime.h>
#include <hip/hip_bf16.h>

#define NNODES 65536
#define NEDGES 262144
#define BATCH  64
#define HDIM   256

// ---------------------------------------------------------------------------
// K1: per-node u[n] = Wf[0:H] . x[n],  v[n] = Wf[H:2H] . x[n]
//     one wave per node, float4 per lane (64*16B = 1KB coalesced row read)
// ---------------------------------------------------------------------------
__global__ __launch_bounds__(256) void k_uv(
    const float* __restrict__ hidden, const int* __restrict__ node_idx,
    const float* __restrict__ Wf, float* __restrict__ u, float* __restrict__ v) {
  int gw   = (blockIdx.x * 256 + threadIdx.x) >> 6;   // global wave = node
  int lane = threadIdx.x & 63;
  if (gw >= NNODES) return;
  const float4* xr = (const float4*)(hidden + (size_t)node_idx[gw] * HDIM);
  float4 xv = xr[lane];
  float4 wa = ((const float4*)Wf)[lane];
  float4 wb = ((const float4*)Wf)[64 + lane];
  float su = xv.x*wa.x + xv.y*wa.y + xv.z*wa.z + xv.w*wa.w;
  float sv = xv.x*wb.x + xv.y*wb.y + xv.z*wb.z + xv.w*wb.w;
  #pragma unroll
  for (int off = 32; off > 0; off >>= 1) {
    su += __shfl_down(su, off);
    sv += __shfl_down(sv, off);
  }
  if (lane == 0) { u[gw] = su; v[gw] = sv; }
}

// ---------------------------------------------------------------------------
// K2: per-edge filter weight w_e = sigmoid(u[row]+v[col]+bf); deg[col] += w_e
// ---------------------------------------------------------------------------
__global__ __launch_bounds__(256) void k_edge_w(
    const int* __restrict__ ei, const float* __restrict__ u,
    const float* __restrict__ v, const float* __restrict__ bf,
    float* __restrict__ wbuf, float* __restrict__ deg) {
  int e = blockIdx.x * 256 + threadIdx.x;
  if (e >= NEDGES) return;
  int r = ei[e], c = ei[NEDGES + e];
  float t = u[r] + v[c] + bf[0];
  float w = 1.0f / (1.0f + __expf(-t));
  wbuf[e] = w;
  unsafeAtomicAdd(&deg[c], w);            // native global_atomic_add_f32
}

// ---------------------------------------------------------------------------
// K3: dis[n] = rsqrt(deg[n]+1); self-loop weight into t; batch counts.
//     t[n][batch[n]] = dis[n]^2 is a plain store (memset'd; unique per n;
//     edge atomics only run in the NEXT kernel).
// ---------------------------------------------------------------------------
__global__ __launch_bounds__(256) void k_dis(
    const int* __restrict__ node_batch, const float* __restrict__ deg,
    float* __restrict__ dis, float* __restrict__ t, int* __restrict__ cnt) {
  int n = blockIdx.x * 256 + threadIdx.x;
  if (n >= NNODES) return;
  float dn = rsqrtf(deg[n] + 1.0f);
  dis[n] = dn;
  int b = node_batch[n];
  t[(size_t)n * BATCH + b] = dn * dn;
  atomicAdd(&cnt[b], 1);
}

// ---------------------------------------------------------------------------
// K4: scatter edge coefficients into t[row][batch[col]] (thread-per-edge).
//     ~4 edges/row -> low atomic contention, fully parallel.
// ---------------------------------------------------------------------------
__global__ __launch_bounds__(256) void k_t(
    const int* __restrict__ ei, const int* __restrict__ node_batch,
    const float* __restrict__ wbuf, const float* __restrict__ dis,
    float* __restrict__ t) {
  int e = blockIdx.x * 256 + threadIdx.x;
  if (e >= NEDGES) return;
  int r = ei[e], c = ei[NEDGES + e];
  float coeff = dis[r] * wbuf[e] * dis[c];
  int b = node_batch[c];
  unsafeAtomicAdd(&t[(size_t)r * BATCH + b], coeff);
}

// ---------------------------------------------------------------------------
// K5: aggT[j][b] = sum_n t[n][b] * x[n][j]   (tall-K GEMM, K = N)
//     lane = b; wave w covers j-quads {w, w+16, w+32, w+48}; block covers the
//     full 64x256 output disjointly over its node chunk. Per node:
//     1 coalesced 256B t-row load + 4 uniform 16B x loads + 16 FMAs.
//     Flush: 16 atomics/thread, contiguous 256B per wave-instr ([j][b] layout).
// ---------------------------------------------------------------------------
__global__ __launch_bounds__(1024) void k_gemm(
    const float* __restrict__ hidden, const int* __restrict__ node_idx,
    const float* __restrict__ t, float* __restrict__ aggT) {
  int lane = threadIdx.x & 63;              // = b
  int w    = threadIdx.x >> 6;              // 0..15
  int n0   = blockIdx.x * (NNODES / 512);   // 128 nodes per block
  float acc[4][4] = {{0.f}};
  #pragma unroll 2
  for (int i = 0; i < NNODES / 512; ++i) {
    int n = n0 + i;
    float tv = t[(size_t)n * BATCH + lane];
    const float* xr = hidden + (size_t)node_idx[n] * HDIM;
    #pragma unroll
    for (int q = 0; q < 4; ++q) {
      float4 xq = *(const float4*)(xr + (w + q * 16) * 4);
      acc[q][0] += tv * xq.x;
      acc[q][1] += tv * xq.y;
      acc[q][2] += tv * xq.z;
      acc[q][3] += tv * xq.w;
    }
  }
  #pragma unroll
  for (int q = 0; q < 4; ++q) {
    int j = (w + q * 16) * 4;
    #pragma unroll
    for (int k = 0; k < 4; ++k)
      unsafeAtomicAdd(&aggT[(size_t)(j + k) * BATCH + lane], acc[q][k]);
  }
}

// ---------------------------------------------------------------------------
// K6: one block per batch b.
//     pooled[k] = (Wc[k,:] . agg[b,:]) / cnt[b] + bc[k]
//     out[b][h] = tanh(Wd[h,:] . pooled + bd[h])
// ---------------------------------------------------------------------------
__global__ __launch_bounds__(256) void k_final(
    const float* __restrict__ aggT, const int* __restrict__ cnt,
    const float* __restrict__ Wc, const float* __restrict__ bc,
    const float* __restrict__ Wd, const float* __restrict__ bd,
    float* __restrict__ out) {
  __shared__ float s_in[HDIM];
  __shared__ float s_mid[HDIM];
  int b = blockIdx.x, tid = threadIdx.x;
  s_in[tid] = aggT[(size_t)tid * BATCH + b];   // transpose gather, tiny
  __syncthreads();
  int lane = tid & 63, wid = tid >> 6;
  float inv = 1.0f / fmaxf((float)cnt[b], 1.0f);
  for (int kk = 0; kk < 64; ++kk) {
    int k = wid * 64 + kk;
    float4 wv = ((const float4*)(Wc + (size_t)k * HDIM))[lane];
    float4 av = ((const float4*)s_in)[lane];
    float p = wv.x*av.x + wv.y*av.y + wv.z*av.z + wv.w*av.w;
    #pragma unroll
    for (int off = 32; off > 0; off >>= 1) p += __shfl_down(p, off);
    if (lane == 0) s_mid[k] = p * inv + bc[k];
  }
  __syncthreads();
  for (int kk = 0; kk < 64; ++kk) {
    int k = wid * 64 + kk;
    float4 wv = ((const float4*)(Wd + (size_t)k * HDIM))[lane];
    float4 av = ((const float4*)s_mid)[lane];
    float p = wv.x*av.x + wv.y*av.y + wv.z*av.z + wv.w*av.w;
    #pragma unroll
    for (int off = 32; off > 0; off >>= 1) p += __shfl_down(p, off);
    if (lane == 0) out[b * HDIM + k] = tanhf(p + bd[k]);
  }
}

// ---------------------------------------------------------------------------
extern "C" void kernel_launch(void* const* d_in, const int* in_sizes, int n_in,
                              void* d_out, int out_size, void* d_ws, size_t ws_size,
                              hipStream_t stream) {
  const float* hidden     = (const float*)d_in[0];
  const int*   node_idx   = (const int*)  d_in[1];
  const int*   ei         = (const int*)  d_in[2];
  const int*   node_batch = (const int*)  d_in[3];
  const float* Wf         = (const float*)d_in[4];
  const float* bf         = (const float*)d_in[5];
  const float* Wc         = (const float*)d_in[6];
  const float* bc         = (const float*)d_in[7];
  const float* Wd         = (const float*)d_in[8];
  const float* bd         = (const float*)d_in[9];
  float* out = (float*)d_out;

  // workspace layout (floats); [t | aggT | deg | cnt] zeroed every call
  float* ws   = (float*)d_ws;
  float* t    = ws;                               // N*64 = 4,194,304
  float* aggT = t + (size_t)NNODES * BATCH;       // 16384  ([j][b])
  float* deg  = aggT + HDIM * BATCH;              // 65536
  int*   cnt  = (int*)(deg + NNODES);             // 64
  float* u    = (float*)(cnt + 64);               // 65536
  float* v    = u + NNODES;                       // 65536
  float* dis  = v + NNODES;                       // 65536
  float* wbuf = dis + NNODES;                     // 262144

  (void)hipMemsetAsync(t, 0,
      ((size_t)NNODES * BATCH + HDIM * BATCH + NNODES + 64) * sizeof(float),
      stream);

  k_uv    <<<NNODES / 4,   256,  0, stream>>>(hidden, node_idx, Wf, u, v);
  k_edge_w<<<NEDGES / 256, 256,  0, stream>>>(ei, u, v, bf, wbuf, deg);
  k_dis   <<<NNODES / 256, 256,  0, stream>>>(node_batch, deg, dis, t, cnt);
  k_t     <<<NEDGES / 256, 256,  0, stream>>>(ei, node_batch, wbuf, dis, t);
  k_gemm  <<<512,          1024, 0, stream>>>(hidden, node_idx, t, aggT);
  k_final <<<BATCH,        256,  0, stream>>>(aggT, cnt, Wc, bc, Wd, bd, out);
}

// Round 4
// 293.902 us; speedup vs baseline: 2.9192x; 2.0222x over previous
//
#include <hip/hip_runtime.h>
#include <hip/hip_bf16.h>

#define NNODES 65536
#define NEDGES 262144
#define BATCH  64
#define HDIM   256

// ---------------------------------------------------------------------------
// K1: per-node u[n] = Wf[0:H] . x[n],  v[n] = Wf[H:2H] . x[n]
//     one wave per node, float4 per lane (64*16B = 1KB coalesced row read)
// ---------------------------------------------------------------------------
__global__ __launch_bounds__(256) void k_uv(
    const float* __restrict__ hidden, const int* __restrict__ node_idx,
    const float* __restrict__ Wf, float* __restrict__ u, float* __restrict__ v) {
  int gw   = (blockIdx.x * 256 + threadIdx.x) >> 6;   // global wave = node
  int lane = threadIdx.x & 63;
  if (gw >= NNODES) return;
  const float4* xr = (const float4*)(hidden + (size_t)node_idx[gw] * HDIM);
  float4 xv = xr[lane];
  float4 wa = ((const float4*)Wf)[lane];
  float4 wb = ((const float4*)Wf)[64 + lane];
  float su = xv.x*wa.x + xv.y*wa.y + xv.z*wa.z + xv.w*wa.w;
  float sv = xv.x*wb.x + xv.y*wb.y + xv.z*wb.z + xv.w*wb.w;
  #pragma unroll
  for (int off = 32; off > 0; off >>= 1) {
    su += __shfl_down(su, off);
    sv += __shfl_down(sv, off);
  }
  if (lane == 0) { u[gw] = su; v[gw] = sv; }
}

// ---------------------------------------------------------------------------
// K2: per-edge filter weight w_e = sigmoid(u[row]+v[col]+bf); deg[col] += w_e
// ---------------------------------------------------------------------------
__global__ __launch_bounds__(256) void k_edge_w(
    const int* __restrict__ ei, const float* __restrict__ u,
    const float* __restrict__ v, const float* __restrict__ bf,
    float* __restrict__ wbuf, float* __restrict__ deg) {
  int e = blockIdx.x * 256 + threadIdx.x;
  if (e >= NEDGES) return;
  int r = ei[e], c = ei[NEDGES + e];
  float t = u[r] + v[c] + bf[0];
  float w = 1.0f / (1.0f + __expf(-t));
  wbuf[e] = w;
  unsafeAtomicAdd(&deg[c], w);            // random addrs, ~4/address: fine
}

// ---------------------------------------------------------------------------
// K3: dis[n] = rsqrt(deg[n]+1); self-loop weight into t. NO atomics.
// ---------------------------------------------------------------------------
__global__ __launch_bounds__(256) void k_dis(
    const int* __restrict__ node_batch, const float* __restrict__ deg,
    float* __restrict__ dis, float* __restrict__ t) {
  int n = blockIdx.x * 256 + threadIdx.x;
  if (n >= NNODES) return;
  float dn = rsqrtf(deg[n] + 1.0f);
  dis[n] = dn;
  t[(size_t)n * BATCH + node_batch[n]] = dn * dn;
}

// ---------------------------------------------------------------------------
// K3b: counts via binary search on the SORTED node_batch (64 threads total).
//      cnt[b] = lower_bound(b+1) - lower_bound(b). Replaces 65536 fully
//      serialized same-address atomics (was 307 us).
// ---------------------------------------------------------------------------
__device__ __forceinline__ int lower_bound_batch(const int* nb, int key) {
  int lo = 0, hi = NNODES;
  while (lo < hi) {
    int mid = (lo + hi) >> 1;
    if (nb[mid] < key) lo = mid + 1; else hi = mid;
  }
  return lo;
}

__global__ __launch_bounds__(64) void k_cnt(
    const int* __restrict__ node_batch, int* __restrict__ cnt) {
  int b = threadIdx.x;   // 0..63
  int s0 = lower_bound_batch(node_batch, b);
  int s1 = lower_bound_batch(node_batch, b + 1);
  cnt[b] = s1 - s0;
}

// ---------------------------------------------------------------------------
// K4: scatter edge coefficients into t[row][batch[col]] (thread-per-edge).
// ---------------------------------------------------------------------------
__global__ __launch_bounds__(256) void k_t(
    const int* __restrict__ ei, const int* __restrict__ node_batch,
    const float* __restrict__ wbuf, const float* __restrict__ dis,
    float* __restrict__ t) {
  int e = blockIdx.x * 256 + threadIdx.x;
  if (e >= NEDGES) return;
  int r = ei[e], c = ei[NEDGES + e];
  float coeff = dis[r] * wbuf[e] * dis[c];
  int b = node_batch[c];
  unsafeAtomicAdd(&t[(size_t)r * BATCH + b], coeff);
}

// ---------------------------------------------------------------------------
// K5: aggT[j][b] = sum_n t[n][b] * x[n][j]   (tall-K GEMM, K = N)
//     lane = b; wave w covers j-quads {w, w+16, w+32, w+48}.
// ---------------------------------------------------------------------------
__global__ __launch_bounds__(1024) void k_gemm(
    const float* __restrict__ hidden, const int* __restrict__ node_idx,
    const float* __restrict__ t, float* __restrict__ aggT) {
  int lane = threadIdx.x & 63;              // = b
  int w    = threadIdx.x >> 6;              // 0..15
  int n0   = blockIdx.x * (NNODES / 512);   // 128 nodes per block
  float acc[4][4] = {{0.f}};
  #pragma unroll 4
  for (int i = 0; i < NNODES / 512; ++i) {
    int n = n0 + i;
    float tv = t[(size_t)n * BATCH + lane];
    const float* xr = hidden + (size_t)node_idx[n] * HDIM;
    #pragma unroll
    for (int q = 0; q < 4; ++q) {
      float4 xq = *(const float4*)(xr + (w + q * 16) * 4);
      acc[q][0] += tv * xq.x;
      acc[q][1] += tv * xq.y;
      acc[q][2] += tv * xq.z;
      acc[q][3] += tv * xq.w;
    }
  }
  #pragma unroll
  for (int q = 0; q < 4; ++q) {
    int j = (w + q * 16) * 4;
    #pragma unroll
    for (int k = 0; k < 4; ++k)
      unsafeAtomicAdd(&aggT[(size_t)(j + k) * BATCH + lane], acc[q][k]);
  }
}

// ---------------------------------------------------------------------------
// K6: one block per batch b.
//     pooled[k] = (Wc[k,:] . agg[b,:]) / cnt[b] + bc[k]
//     out[b][h] = tanh(Wd[h,:] . pooled + bd[h])
// ---------------------------------------------------------------------------
__global__ __launch_bounds__(256) void k_final(
    const float* __restrict__ aggT, const int* __restrict__ cnt,
    const float* __restrict__ Wc, const float* __restrict__ bc,
    const float* __restrict__ Wd, const float* __restrict__ bd,
    float* __restrict__ out) {
  __shared__ float s_in[HDIM];
  __shared__ float s_mid[HDIM];
  int b = blockIdx.x, tid = threadIdx.x;
  s_in[tid] = aggT[(size_t)tid * BATCH + b];   // transpose gather, tiny
  __syncthreads();
  int lane = tid & 63, wid = tid >> 6;
  float inv = 1.0f / fmaxf((float)cnt[b], 1.0f);
  for (int kk = 0; kk < 64; ++kk) {
    int k = wid * 64 + kk;
    float4 wv = ((const float4*)(Wc + (size_t)k * HDIM))[lane];
    float4 av = ((const float4*)s_in)[lane];
    float p = wv.x*av.x + wv.y*av.y + wv.z*av.z + wv.w*av.w;
    #pragma unroll
    for (int off = 32; off > 0; off >>= 1) p += __shfl_down(p, off);
    if (lane == 0) s_mid[k] = p * inv + bc[k];
  }
  __syncthreads();
  for (int kk = 0; kk < 64; ++kk) {
    int k = wid * 64 + kk;
    float4 wv = ((const float4*)(Wd + (size_t)k * HDIM))[lane];
    float4 av = ((const float4*)s_mid)[lane];
    float p = wv.x*av.x + wv.y*av.y + wv.z*av.z + wv.w*av.w;
    #pragma unroll
    for (int off = 32; off > 0; off >>= 1) p += __shfl_down(p, off);
    if (lane == 0) out[b * HDIM + k] = tanhf(p + bd[k]);
  }
}

// ---------------------------------------------------------------------------
extern "C" void kernel_launch(void* const* d_in, const int* in_sizes, int n_in,
                              void* d_out, int out_size, void* d_ws, size_t ws_size,
                              hipStream_t stream) {
  const float* hidden     = (const float*)d_in[0];
  const int*   node_idx   = (const int*)  d_in[1];
  const int*   ei         = (const int*)  d_in[2];
  const int*   node_batch = (const int*)  d_in[3];
  const float* Wf         = (const float*)d_in[4];
  const float* bf         = (const float*)d_in[5];
  const float* Wc         = (const float*)d_in[6];
  const float* bc         = (const float*)d_in[7];
  const float* Wd         = (const float*)d_in[8];
  const float* bd         = (const float*)d_in[9];
  float* out = (float*)d_out;

  // workspace layout (floats); [t | aggT | deg | cnt] zeroed every call
  float* ws   = (float*)d_ws;
  float* t    = ws;                               // N*64 = 4,194,304
  float* aggT = t + (size_t)NNODES * BATCH;       // 16384  ([j][b])
  float* deg  = aggT + HDIM * BATCH;              // 65536
  int*   cnt  = (int*)(deg + NNODES);             // 64
  float* u    = (float*)(cnt + 64);               // 65536
  float* v    = u + NNODES;                       // 65536
  float* dis  = v + NNODES;                       // 65536
  float* wbuf = dis + NNODES;                     // 262144

  (void)hipMemsetAsync(t, 0,
      ((size_t)NNODES * BATCH + HDIM * BATCH + NNODES + 64) * sizeof(float),
      stream);

  k_uv    <<<NNODES / 4,   256,  0, stream>>>(hidden, node_idx, Wf, u, v);
  k_edge_w<<<NEDGES / 256, 256,  0, stream>>>(ei, u, v, bf, wbuf, deg);
  k_dis   <<<NNODES / 256, 256,  0, stream>>>(node_batch, deg, dis, t);
  k_cnt   <<<1,            64,   0, stream>>>(node_batch, cnt);
  k_t     <<<NEDGES / 256, 256,  0, stream>>>(ei, node_batch, wbuf, dis, t);
  k_gemm  <<<512,          1024, 0, stream>>>(hidden, node_idx, t, aggT);
  k_final <<<BATCH,        256,  0, stream>>>(aggT, cnt, Wc, bc, Wd, bd, out);
}